// Round 1
// baseline (336.360 us; speedup 1.0000x reference)
//
#include <hip/hip_runtime.h>
#include <stdint.h>

#define M_ROWS 8192
#define N_COLS 16384
#define D_DIM  512
#define NNZ_N  65536
#define CHUNKS 8                 // N-chunks; each chunk = 2048 cols = 16 tiles of 128
#define NT_PER_CHUNK 16
#define PARTS  (CHUNKS*2)        // per-row partials: chunk x wave-column-half
#define EPSF   1e-20f

typedef __attribute__((ext_vector_type(4))) float  f32x4;
typedef __attribute__((ext_vector_type(8))) __bf16 bf16x8;

// ---------------- fp32 -> bf16 (RNE) ----------------
__device__ __forceinline__ uint16_t f32_to_bf16(float f) {
    uint32_t u = __float_as_uint(f);
    return (uint16_t)((u + 0x7FFFu + ((u >> 16) & 1u)) >> 16);
}

__global__ void convert_bf16(const float* __restrict__ in, uint16_t* __restrict__ out, int n4) {
    int stride = gridDim.x * blockDim.x;
    for (int idx = blockIdx.x * blockDim.x + threadIdx.x; idx < n4; idx += stride) {
        float4 v = ((const float4*)in)[idx];
        ushort4 o;
        o.x = f32_to_bf16(v.x); o.y = f32_to_bf16(v.y);
        o.z = f32_to_bf16(v.z); o.w = f32_to_bf16(v.w);
        ((ushort4*)out)[idx] = o;
    }
}

// ---------------- pos_sum: sum of Y[r,c] over 65536 coordinates ----------------
__global__ void pos_kernel(const float* __restrict__ P, const float* __restrict__ Q,
                           const int* __restrict__ rows, const int* __restrict__ cols,
                           float* __restrict__ acc) {
    int lane = threadIdx.x & 63;
    int gwave = (blockIdx.x * blockDim.x + threadIdx.x) >> 6;   // 1024 waves
    float part = 0.f;
    for (int idx = gwave; idx < NNZ_N; idx += 1024) {
        int r = rows[idx], c = cols[idx];
        const float4* pr = (const float4*)(P + (size_t)r * D_DIM);
        const float4* qr = (const float4*)(Q + (size_t)c * D_DIM);
        float4 p0 = pr[lane * 2], p1 = pr[lane * 2 + 1];
        float4 q0 = qr[lane * 2], q1 = qr[lane * 2 + 1];
        part += p0.x*q0.x + p0.y*q0.y + p0.z*q0.z + p0.w*q0.w
              + p1.x*q1.x + p1.y*q1.y + p1.z*q1.z + p1.w*q1.w;
    }
    #pragma unroll
    for (int m = 32; m; m >>= 1) part += __shfl_xor(part, m);
    if (lane == 0) atomicAdd(acc, part);
}

// ---------------- async global->LDS, 16B per lane ----------------
__device__ __forceinline__ void gload_lds16(const void* g, void* l) {
    __builtin_amdgcn_global_load_lds((const __attribute__((address_space(1))) unsigned int*)g,
                                     (__attribute__((address_space(3))) unsigned int*)l,
                                     16, 0, 0);
}

// ---------------- flash GEMM + online weighted softmax-denominator ----------------
// grid (64 row-blocks, 8 chunks), 256 threads (4 waves, 2x2 of 64x64)
__launch_bounds__(256, 2)
__global__ void flash_gemm(const uint16_t* __restrict__ Pb, const uint16_t* __restrict__ Qb,
                           const float* __restrict__ Bw, float* __restrict__ partials) {
    __shared__ uint16_t ldsP[128 * 32];   // 8 KB, row-major [row][k]
    __shared__ uint16_t ldsQ[128 * 32];   // 8 KB

    const int tid  = threadIdx.x;
    const int lane = tid & 63;
    const int w    = tid >> 6;
    const int wr   = w >> 1;          // wave row 0..1
    const int wc   = w & 1;           // wave col 0..1
    const int brow = blockIdx.x * 128;
    const int chunk = blockIdx.y;
    const int col0 = chunk * (N_COLS / CHUNKS);

    const int fr = lane & 15;         // fragment row/col within 16
    const int fq = lane >> 4;         // k-group (8 contiguous bf16)

    // per-lane online state: 16 row slots (m-frag x reg), over this lane's columns
    float m_run[16], s_run[16];
    #pragma unroll
    for (int s = 0; s < 16; ++s) { m_run[s] = -INFINITY; s_run[s] = 0.f; }

    for (int nt = 0; nt < NT_PER_CHUNK; ++nt) {
        const int qrow0 = col0 + nt * 128;

        f32x4 acc[4][4];
        #pragma unroll
        for (int i = 0; i < 4; ++i)
            #pragma unroll
            for (int j = 0; j < 4; ++j)
                acc[i][j] = (f32x4){0.f, 0.f, 0.f, 0.f};

        for (int kt = 0; kt < D_DIM; kt += 32) {
            __syncthreads();   // previous iteration's LDS reads complete
            // stage P/Q tiles: 8KB each, 8 chunks of 1KB (16 rows) per tile
            #pragma unroll
            for (int r = 0; r < 2; ++r) {
                const int c = r * 4 + w;                 // 1KB chunk id 0..7
                const int row = c * 16 + (lane >> 2);
                const int ke  = (lane & 3) * 8;
                gload_lds16(Pb + (size_t)(brow + row) * D_DIM + kt + ke, &ldsP[c * 512]);
                gload_lds16(Qb + (size_t)(qrow0 + row) * D_DIM + kt + ke, &ldsQ[c * 512]);
            }
            __syncthreads();   // compiler emits vmcnt(0)+lgkmcnt(0) before barrier

            bf16x8 af[4], bfr[4];
            #pragma unroll
            for (int m = 0; m < 4; ++m)
                af[m] = *(const bf16x8*)&ldsP[(wr * 64 + m * 16 + fr) * 32 + fq * 8];
            #pragma unroll
            for (int n = 0; n < 4; ++n)
                bfr[n] = *(const bf16x8*)&ldsQ[(wc * 64 + n * 16 + fr) * 32 + fq * 8];
            #pragma unroll
            for (int m = 0; m < 4; ++m)
                #pragma unroll
                for (int n = 0; n < 4; ++n)
                    acc[m][n] = __builtin_amdgcn_mfma_f32_16x16x32_bf16(af[m], bfr[n], acc[m][n], 0, 0, 0);
        }

        // epilogue: online update. lane's columns: qrow0 + wc*64 + n*16 + fr
        float bwv[4];
        #pragma unroll
        for (int n = 0; n < 4; ++n) bwv[n] = Bw[qrow0 + wc * 64 + n * 16 + fr];

        #pragma unroll
        for (int m = 0; m < 4; ++m) {
            #pragma unroll
            for (int j = 0; j < 4; ++j) {
                const int s = m * 4 + j;
                float v0 = acc[m][0][j], v1 = acc[m][1][j], v2 = acc[m][2][j], v3 = acc[m][3][j];
                float vmax = fmaxf(fmaxf(v0, v1), fmaxf(v2, v3));
                float mn = fmaxf(m_run[s], vmax);
                float scale = __expf(m_run[s] - mn);
                float add = __expf(v0 - mn) * bwv[0] + __expf(v1 - mn) * bwv[1]
                          + __expf(v2 - mn) * bwv[2] + __expf(v3 - mn) * bwv[3];
                s_run[s] = s_run[s] * scale + add;
                m_run[s] = mn;
            }
        }
    }

    // merge across the 16 lanes sharing the same rows (lane>>4 group preserved)
    #pragma unroll
    for (int s = 0; s < 16; ++s) {
        float m = m_run[s], sm = s_run[s];
        #pragma unroll
        for (int msk = 1; msk < 16; msk <<= 1) {
            float mo = __shfl_xor(m, msk);
            float so = __shfl_xor(sm, msk);
            float mn = fmaxf(m, mo);
            sm = sm * __expf(m - mn) + so * __expf(mo - mn);
            m = mn;
        }
        m_run[s] = m; s_run[s] = sm;
    }
    if ((lane & 15) == 0) {
        const int g = lane >> 4;
        #pragma unroll
        for (int mfrag = 0; mfrag < 4; ++mfrag)
            #pragma unroll
            for (int j = 0; j < 4; ++j) {
                const int s = mfrag * 4 + j;
                const int row = brow + wr * 64 + mfrag * 16 + g * 4 + j;
                ((float2*)partials)[(size_t)row * PARTS + chunk * 2 + wc] =
                    make_float2(m_run[s], s_run[s]);
            }
    }
}

// ---------------- finalize: merge partials -> wlse -> weighted sum ----------------
__global__ void finalize(const float* __restrict__ partials, const float* __restrict__ A,
                         const float* __restrict__ Ab, float* __restrict__ acc) {
    int i = blockIdx.x * blockDim.x + threadIdx.x;   // 8192 threads
    const float2* p = (const float2*)partials + (size_t)i * PARTS;
    float m = -INFINITY, s = 0.f;
    #pragma unroll
    for (int k = 0; k < PARTS; ++k) {
        float2 ps = p[k];
        float mn = fmaxf(m, ps.x);
        s = s * __expf(m - mn) + ps.y * __expf(ps.x - mn);
        m = mn;
    }
    float wlse = m + __logf(s + EPSF);
    float val = A[i] / Ab[i] * wlse;

    #pragma unroll
    for (int msk = 32; msk; msk >>= 1) val += __shfl_xor(val, msk);
    __shared__ float wsum[4];
    int lane = threadIdx.x & 63, wv = threadIdx.x >> 6;
    if (lane == 0) wsum[wv] = val;
    __syncthreads();
    if (threadIdx.x == 0) atomicAdd(acc + 1, wsum[0] + wsum[1] + wsum[2] + wsum[3]);
}

__global__ void write_out(const float* __restrict__ acc, float* __restrict__ out) {
    out[0] = acc[1] - acc[0];    // loss = OMEGA*sum_wlse - pos_sum, OMEGA=1
}

extern "C" void kernel_launch(void* const* d_in, const int* in_sizes, int n_in,
                              void* d_out, int out_size, void* d_ws, size_t ws_size,
                              hipStream_t stream) {
    const float* P  = (const float*)d_in[0];
    const float* Q  = (const float*)d_in[1];
    const float* A  = (const float*)d_in[2];
    const float* B  = (const float*)d_in[3];
    const float* Ab = (const float*)d_in[4];
    // d_in[5] = Bb (unused by reference)
    const int* rows = (const int*)d_in[6];
    const int* cols = (const int*)d_in[7];

    char* ws = (char*)d_ws;
    uint16_t* Pb       = (uint16_t*)ws;                          // 8 MB
    uint16_t* Qb       = (uint16_t*)(ws + 8ull  * 1024 * 1024);  // 16 MB
    float*    partials = (float*)   (ws + 24ull * 1024 * 1024);  // 1 MB (8192*16*float2)
    float*    acc      = (float*)   (ws + 26ull * 1024 * 1024);  // acc[0]=pos, acc[1]=wlse-sum

    hipMemsetAsync(acc, 0, 2 * sizeof(float), stream);
    convert_bf16<<<1024, 256, 0, stream>>>(P, Pb, M_ROWS * D_DIM / 4);
    convert_bf16<<<2048, 256, 0, stream>>>(Q, Qb, N_COLS * D_DIM / 4);
    pos_kernel<<<256, 256, 0, stream>>>(P, Q, rows, cols, acc);
    flash_gemm<<<dim3(M_ROWS / 128, CHUNKS), 256, 0, stream>>>(Pb, Qb, B, partials);
    finalize<<<M_ROWS / 256, 256, 0, stream>>>(partials, A, Ab, acc);
    write_out<<<1, 1, 0, stream>>>(acc, (float*)d_out);
}